// Round 7
// baseline (4146.171 us; speedup 1.0000x reference)
//
#include <hip/hip_runtime.h>
#include <math.h>
#include <cstddef>

#define NNODES 32768
#define NEDGES 262144
#define NB 32

__device__ __forceinline__ void load8f(const float* p, float* o) {
  float4 a = *reinterpret_cast<const float4*>(p);
  float4 b = *reinterpret_cast<const float4*>(p + 4);
  o[0] = a.x; o[1] = a.y; o[2] = a.z; o[3] = a.w;
  o[4] = b.x; o[5] = b.y; o[6] = b.z; o[7] = b.w;
}

__global__ void GraphEncoder_82575041233261_kernel() {}

__global__ void fill_f32(float* p, float v, int n) {
  int i = blockIdx.x * blockDim.x + threadIdx.x;
  if (i < n) p[i] = v;
}
__global__ void fill_i32(int* p, int v, int n) {
  int i = blockIdx.x * blockDim.x + threadIdx.x;
  if (i < n) p[i] = v;
}

__global__ void edge_init(const int* __restrict__ ei, const float* __restrict__ ew,
                          int* ei0, int* ei1, float* ewf, int* emask) {
  int e = blockIdx.x * blockDim.x + threadIdx.x;
  if (e >= NEDGES) return;
  ei0[e] = ei[e];
  ei1[e] = ei[NEDGES + e];
  ewf[e] = ew[e];
  emask[e] = 1;
}

// C[n,M] = A[n,K] @ W[K,M] (+bias) (relu optional). 64x64 tile, 256 thr.
__global__ __launch_bounds__(256) void gemm_bias(
    const float* __restrict__ A, const float* __restrict__ W,
    const float* __restrict__ bias, float* __restrict__ C,
    int n, int K, int M, int relu) {
  __shared__ float As[16][64];
  __shared__ float Ws[16][64];
  const int tid = threadIdx.x;
  const int tx = tid & 15, ty = tid >> 4;
  const int row0 = blockIdx.x * 64, col0 = blockIdx.y * 64;
  float acc[4][4] = {{0.f}, {0.f}, {0.f}, {0.f}};
  for (int kt = 0; kt < K; kt += 16) {
#pragma unroll
    for (int i = 0; i < 4; i++) {
      int idx = tid + i * 256;
      int m = idx >> 4, kk = idx & 15;
      As[kk][m] = A[(size_t)(row0 + m) * K + kt + kk];
    }
#pragma unroll
    for (int i = 0; i < 4; i++) {
      int idx = tid + i * 256;
      int nn = idx & 63, kk = idx >> 6;
      Ws[kk][nn] = W[(size_t)(kt + kk) * M + col0 + nn];
    }
    __syncthreads();
#pragma unroll
    for (int kk = 0; kk < 16; kk++) {
      float a[4], b[4];
#pragma unroll
      for (int i = 0; i < 4; i++) a[i] = As[kk][ty * 4 + i];
#pragma unroll
      for (int j = 0; j < 4; j++) b[j] = Ws[kk][tx * 4 + j];
#pragma unroll
      for (int i = 0; i < 4; i++)
#pragma unroll
        for (int j = 0; j < 4; j++) acc[i][j] += a[i] * b[j];
    }
    __syncthreads();
  }
#pragma unroll
  for (int i = 0; i < 4; i++)
#pragma unroll
    for (int j = 0; j < 4; j++) {
      int cc = col0 + tx * 4 + j;
      float v = acc[i][j] + (bias ? bias[cc] : 0.f);
      if (relu) v = fmaxf(v, 0.f);
      C[(size_t)(row0 + ty * 4 + i) * M + cc] = v;
    }
}

// Ct[cin, h*128+co] = sum_c Wq[cin,h128+c]*Wk[co,h128+c]
__global__ __launch_bounds__(256) void prep_ct(const float* __restrict__ Wq,
                                               const float* __restrict__ Wk,
                                               float* __restrict__ Ct) {
  int idx = blockIdx.x * 256 + threadIdx.x;  // 65536
  int cin = idx >> 9, r = idx & 511, h = r >> 7, co = r & 127;
  float acc = 0.f;
  for (int c = 0; c < 128; c++)
    acc += Wq[cin * 512 + h * 128 + c] * Wk[co * 512 + h * 128 + c];
  Ct[idx] = acc;
}
// Bt[cin, h*64+f] = sum_c Wq[cin,h128+c]*EWm[f,h128+c]; gb[h64+f]=sum_c EWm*bq
__global__ __launch_bounds__(256) void prep_bt(const float* __restrict__ Wq,
                                               const float* __restrict__ EWm,
                                               const float* __restrict__ bq,
                                               float* __restrict__ Bt, float* __restrict__ gb) {
  int idx = blockIdx.x * 256 + threadIdx.x;  // 32768
  int cin = idx >> 8, r = idx & 255, h = r >> 6, f = r & 63;
  float acc = 0.f;
  for (int c = 0; c < 128; c++)
    acc += Wq[cin * 512 + h * 128 + c] * EWm[f * 512 + h * 128 + c];
  Bt[idx] = acc;
  if (cin == 0) {
    float s = 0.f;
    for (int c = 0; c < 128; c++)
      s += EWm[f * 512 + h * 128 + c] * bq[h * 128 + c];
    gb[r] = s;
  }
}
// WCR[cin,j]: j<4 -> colS (Wq*(bk+eb)); j>=4 -> rowS (Wk*bq). CC[h]=bq*(bk+eb)
__global__ __launch_bounds__(1024) void prep_sc(const float* __restrict__ Wq,
                                                const float* __restrict__ Wk,
                                                const float* __restrict__ bq,
                                                const float* __restrict__ bk,
                                                const float* __restrict__ eb,
                                                float* __restrict__ WCR, float* __restrict__ CC) {
  int tid = threadIdx.x;
  int cin = tid >> 3, j = tid & 7, h = j & 3, isR = j >> 2;
  float acc = 0.f;
  if (isR) {
    for (int c = 0; c < 128; c++)
      acc += Wk[cin * 512 + h * 128 + c] * bq[h * 128 + c];
  } else {
    for (int c = 0; c < 128; c++)
      acc += Wq[cin * 512 + h * 128 + c] * (bk[h * 128 + c] + eb[h * 128 + c]);
  }
  WCR[cin * 8 + j] = acc;
  if (tid < 4) {
    float s = 0.f;
    for (int c = 0; c < 128; c++)
      s += bq[tid * 128 + c] * (bk[tid * 128 + c] + eb[tid * 128 + c]);
    CC[tid] = s;
  }
}
// SCV[node, j] = XL[node]·WCR[:,j] (+CC for j<4)
__global__ __launch_bounds__(256) void node_scalars(const float* __restrict__ XL,
                                                    const float* __restrict__ WCR,
                                                    const float* __restrict__ CC,
                                                    float* __restrict__ SCV, int n) {
  int t = blockIdx.x * 256 + threadIdx.x;
  if (t >= n * 8) return;
  int node = t >> 3, j = t & 7;
  const float* xr = XL + (size_t)node * 128;
  float acc = (j < 4) ? CC[j] : 0.f;
  for (int c = 0; c < 128; c++) acc += xr[c] * WCR[c * 8 + j];
  SCV[t] = acc;
}

__global__ void deg_count(const int* __restrict__ ei0, const int* __restrict__ emask,
                          float* deg) {
  int e = blockIdx.x * blockDim.x + threadIdx.x;
  if (e >= NEDGES) return;
  if (emask[e]) atomicAdd(&deg[ei0[e]], 1.0f);
}
__global__ void dis_finish(float* dis, int n) {
  int i = blockIdx.x * blockDim.x + threadIdx.x;
  if (i >= n) return;
  float d = dis[i];
  dis[i] = d > 0.f ? rsqrtf(d) : 0.f;
}
__global__ void cnt_count(const int* __restrict__ ei1, const int* __restrict__ emask,
                          int* cnt) {
  int e = blockIdx.x * blockDim.x + threadIdx.x;
  if (e >= NEDGES) return;
  if (emask[e]) atomicAdd(&cnt[ei1[e]], 1);
}
__global__ __launch_bounds__(1024) void scan_kernel(const int* __restrict__ cnt,
                                                    int* indptr, int* cursor, int n) {
  __shared__ int part[1024];
  int tid = threadIdx.x;
  int per = n / 1024;
  int base = tid * per;
  int s = 0;
  for (int j = 0; j < per; j++) s += cnt[base + j];
  part[tid] = s;
  __syncthreads();
  for (int d = 1; d < 1024; d <<= 1) {
    int t = (tid >= d) ? part[tid - d] : 0;
    __syncthreads();
    part[tid] += t;
    __syncthreads();
  }
  int run = part[tid] - s;  // exclusive
  for (int j = 0; j < per; j++) {
    indptr[base + j] = run;
    cursor[base + j] = run;
    run += cnt[base + j];
  }
  if (tid == 1023) indptr[n] = run;
}
__global__ void csr_fill(const int* __restrict__ ei1, const int* __restrict__ emask,
                         int* cursor, int* csre) {
  int e = blockIdx.x * blockDim.x + threadIdx.x;
  if (e >= NEDGES) return;
  if (!emask[e]) return;
  int p = atomicAdd(&cursor[ei1[e]], 1);
  csre[p] = e;
}

// ---- fused attention: one wave per destination node (OUT aliases Uv; each wave
// reads only its own U row before writing the same row) ----
__global__ __launch_bounds__(256) void fused_attn(
    const int* __restrict__ EI0v, const float* __restrict__ EWFv,
    const int* __restrict__ indptr, const int* __restrict__ csre,
    const float* __restrict__ EA, const float* __restrict__ XLv,
    const float* Uv, const float* __restrict__ Gv,
    const float* __restrict__ SCVv, const float* __restrict__ DISv,
    const float* __restrict__ Wv, const float* __restrict__ EWm,
    const float* __restrict__ Sw, const float* __restrict__ vb,
    const float* __restrict__ eb, const float* __restrict__ sb,
    float* OUT) {
  __shared__ float zs[4][520];
  __shared__ float wsW[4][260];
  __shared__ float xls[4][128];
  __shared__ float xwls[4][128];
  const int w = threadIdx.x >> 6, lane = threadIdx.x & 63;
  const int h = lane >> 4, t16 = lane & 15;
  const int col = blockIdx.x * 4 + w;
  float u8[8];
  load8f(Uv + (size_t)col * 512 + lane * 8, u8);
  float4 g4 = *reinterpret_cast<const float4*>(Gv + (size_t)col * 256 + lane * 4);
  const float colS = SCVv[col * 8 + h];
  xls[w][lane * 2] = XLv[(size_t)col * 128 + lane * 2];
  xls[w][lane * 2 + 1] = XLv[(size_t)col * 128 + lane * 2 + 1];
  const float dcol = DISv[col];
  const int beg = indptr[col], end = indptr[col + 1];
  const float rs = 0.08838834764831845f;  // 1/sqrt(128)
  float m = -3.0e38f;
  for (int i = beg; i < end; i++) {
    const int e = csre[i];
    const int r = EI0v[e];
    float xr[8];
    load8f(XLv + (size_t)r * 128 + t16 * 8, xr);
    float4 ea4 = *reinterpret_cast<const float4*>(EA + (size_t)e * 64 + t16 * 4);
    float pa = 0.f;
#pragma unroll
    for (int j = 0; j < 8; j++) pa += u8[j] * xr[j];
    pa += g4.x * ea4.x + g4.y * ea4.y + g4.z * ea4.z + g4.w * ea4.w;
    pa += __shfl_xor(pa, 1);
    pa += __shfl_xor(pa, 2);
    pa += __shfl_xor(pa, 4);
    pa += __shfl_xor(pa, 8);
    float alpha = (pa + colS + SCVv[r * 8 + 4 + h]) * rs;
    m = fmaxf(m, alpha);
  }
  if (beg == end) m = 0.f;  // matches reference amax isfinite fixup
  float den = 0.f;
  float z8[8] = {0.f, 0.f, 0.f, 0.f, 0.f, 0.f, 0.f, 0.f};
  float w4[4] = {0.f, 0.f, 0.f, 0.f};
  float xw0 = 0.f, xw1 = 0.f;
  for (int i = beg; i < end; i++) {
    const int e = csre[i];
    const int r = EI0v[e];
    float xr[8];
    load8f(XLv + (size_t)r * 128 + t16 * 8, xr);
    float4 ea4 = *reinterpret_cast<const float4*>(EA + (size_t)e * 64 + t16 * 4);
    float pa = 0.f;
#pragma unroll
    for (int j = 0; j < 8; j++) pa += u8[j] * xr[j];
    pa += g4.x * ea4.x + g4.y * ea4.y + g4.z * ea4.z + g4.w * ea4.w;
    pa += __shfl_xor(pa, 1);
    pa += __shfl_xor(pa, 2);
    pa += __shfl_xor(pa, 4);
    pa += __shfl_xor(pa, 8);
    float alpha = (pa + colS + SCVv[r * 8 + 4 + h]) * rs;
    float a = expf(alpha - m);
    den += a;
#pragma unroll
    for (int j = 0; j < 8; j++) z8[j] += a * xr[j];
    w4[0] += a * ea4.x; w4[1] += a * ea4.y; w4[2] += a * ea4.z; w4[3] += a * ea4.w;
    const float norm = DISv[r] * EWFv[e] * dcol;
    xw0 += norm * XLv[(size_t)r * 128 + lane * 2];
    xw1 += norm * XLv[(size_t)r * 128 + lane * 2 + 1];
  }
#pragma unroll
  for (int j = 0; j < 8; j++) zs[w][h * 130 + t16 * 8 + j] = z8[j];
#pragma unroll
  for (int j = 0; j < 4; j++) wsW[w][h * 65 + t16 * 4 + j] = w4[j];
  xwls[w][lane * 2] = xw0;
  xwls[w][lane * 2 + 1] = xw1;
  __syncthreads();
  const float inv = 1.f / (den + 1e-16f);
  const int o0 = lane * 8;  // == h*128 + t16*8
  float acc8[8];
#pragma unroll
  for (int j = 0; j < 8; j++) acc8[j] = den * (vb[o0 + j] + eb[o0 + j]);
  for (int cin = 0; cin < 128; cin++) {
    const float zc = zs[w][h * 130 + cin];
    float4 a = *reinterpret_cast<const float4*>(Wv + (size_t)cin * 512 + o0);
    float4 b = *reinterpret_cast<const float4*>(Wv + (size_t)cin * 512 + o0 + 4);
    acc8[0] += zc * a.x; acc8[1] += zc * a.y; acc8[2] += zc * a.z; acc8[3] += zc * a.w;
    acc8[4] += zc * b.x; acc8[5] += zc * b.y; acc8[6] += zc * b.z; acc8[7] += zc * b.w;
  }
  for (int f = 0; f < 64; f++) {
    const float wc = wsW[w][h * 65 + f];
    float4 a = *reinterpret_cast<const float4*>(EWm + (size_t)f * 512 + o0);
    float4 b = *reinterpret_cast<const float4*>(EWm + (size_t)f * 512 + o0 + 4);
    acc8[0] += wc * a.x; acc8[1] += wc * a.y; acc8[2] += wc * a.z; acc8[3] += wc * a.w;
    acc8[4] += wc * b.x; acc8[5] += wc * b.y; acc8[6] += wc * b.z; acc8[7] += wc * b.w;
  }
#pragma unroll
  for (int j = 0; j < 8; j++) acc8[j] = acc8[j] * inv + sb[o0 + j];
  for (int cin = 0; cin < 128; cin++) {
    const float xc = xls[w][cin];
    float4 a = *reinterpret_cast<const float4*>(Sw + (size_t)cin * 512 + o0);
    float4 b = *reinterpret_cast<const float4*>(Sw + (size_t)cin * 512 + o0 + 4);
    acc8[0] += xc * a.x; acc8[1] += xc * a.y; acc8[2] += xc * a.z; acc8[3] += xc * a.w;
    acc8[4] += xc * b.x; acc8[5] += xc * b.y; acc8[6] += xc * b.z; acc8[7] += xc * b.w;
  }
#pragma unroll
  for (int j = 0; j < 8; j++) acc8[j] += xwls[w][t16 * 8 + j];
  float4 o1, o2;
  o1.x = acc8[0]; o1.y = acc8[1]; o1.z = acc8[2]; o1.w = acc8[3];
  o2.x = acc8[4]; o2.y = acc8[5]; o2.z = acc8[6]; o2.w = acc8[7];
  *reinterpret_cast<float4*>(OUT + (size_t)col * 512 + o0) = o1;
  *reinterpret_cast<float4*>(OUT + (size_t)col * 512 + o0 + 4) = o2;
}

// ---- batchnorm on fp32 buffer (in-place) ----
__global__ __launch_bounds__(256) void bn_accum(const float* __restrict__ x,
                                                float* s1, float* s2, int n) {
  int c = threadIdx.x & 127;
  int half = threadIdx.x >> 7;
  float a = 0.f, b = 0.f;
  for (int i = blockIdx.x * 2 + half; i < n; i += gridDim.x * 2) {
    float v = x[(size_t)i * 128 + c];
    a += v;
    b += v * v;
  }
  atomicAdd(&s1[c], a);
  atomicAdd(&s2[c], b);
}
__global__ void bn_final(const float* s1, const float* s2, float* mu, float* rstd, int n) {
  int c = threadIdx.x;
  if (c >= 128) return;
  float m = s1[c] / (float)n;
  mu[c] = m;
  float var = s2[c] / (float)n - m * m;
  rstd[c] = rsqrtf(var + 1e-5f);
}
__global__ void bn_apply(float* x, const float* __restrict__ mu,
                         const float* __restrict__ rstd, const float* __restrict__ g,
                         const float* __restrict__ b, int n) {
  int t = blockIdx.x * blockDim.x + threadIdx.x;
  if (t >= n * 128) return;
  int c = t & 127;
  x[t] = g[c] * (x[t] - mu[c]) * rstd[c] + b[c];
}

// ---- pooling ----
__global__ void wnorm_kernel(const float* __restrict__ w, float* wn) {
  __shared__ float s[128];
  int t = threadIdx.x;
  float v = w[t];
  s[t] = v * v;
  __syncthreads();
  for (int st = 64; st > 0; st >>= 1) {
    if (t < st) s[t] += s[t + st];
    __syncthreads();
  }
  if (t == 0) wn[0] = sqrtf(s[0]) + 1e-16f;
}
__global__ void score_kernel(const float* __restrict__ h, const float* __restrict__ w,
                             const float* __restrict__ wn, float* s, int n) {
  int i = blockIdx.x * blockDim.x + threadIdx.x;
  if (i >= n) return;
  float d = 0.f;
  for (int c = 0; c < 128; c++) d += h[(size_t)i * 128 + c] * w[c];
  s[i] = tanhf(d / wn[0]);
}
// per-graph bitonic top-k (desc, tie -> lower index, like lax.top_k)
__global__ __launch_bounds__(512) void topk_kernel(const float* __restrict__ s,
                                                   float* gateVal, int* selIdx,
                                                   int* newid, int M) {
  __shared__ float sv[1024];
  __shared__ int si[1024];
  const int g = blockIdx.x;
  const int k = M >> 1;
  for (int t = threadIdx.x; t < 1024; t += 512) {
    if (t < M) {
      sv[t] = s[(size_t)g * M + t];
      si[t] = t;
    } else {
      sv[t] = -3.4e38f;
      si[t] = 0x7fffffff;
    }
  }
  __syncthreads();
  for (int kk = 2; kk <= 1024; kk <<= 1) {
    for (int j = kk >> 1; j > 0; j >>= 1) {
      for (int t = threadIdx.x; t < 1024; t += 512) {
        int p = t ^ j;
        if (p > t) {
          float va = sv[t], vb2 = sv[p];
          int ia = si[t], ib = si[p];
          bool beforeBA = (vb2 > va) || (vb2 == va && ib < ia);
          bool beforeAB = (va > vb2) || (va == vb2 && ia < ib);
          bool dir = ((t & kk) == 0);
          bool sw = dir ? beforeBA : beforeAB;
          if (sw) {
            sv[t] = vb2;
            sv[p] = va;
            si[t] = ib;
            si[p] = ia;
          }
        }
      }
      __syncthreads();
    }
  }
  for (int j = threadIdx.x; j < k; j += 512) {
    int oldg = g * M + si[j];
    int newg = g * k + j;
    gateVal[newg] = sv[j];
    selIdx[newg] = oldg;
    newid[oldg] = newg;
  }
}
__global__ void gate_kernel(const float* __restrict__ hOld, const float* __restrict__ gv,
                            const int* __restrict__ sel, float* __restrict__ hNew,
                            int nNew) {
  int t = blockIdx.x * blockDim.x + threadIdx.x;
  if (t >= nNew * 128) return;
  int i = t >> 7, c = t & 127;
  hNew[t] = hOld[(size_t)sel[i] * 128 + c] * gv[i];
}
__global__ void relabel_kernel(int* ei0, int* ei1, float* ewf, int* emask,
                               const int* __restrict__ newid) {
  int e = blockIdx.x * blockDim.x + threadIdx.x;
  if (e >= NEDGES) return;
  int nr = newid[ei0[e]];
  int nc = newid[ei1[e]];
  int keep = (nr >= 0 && nc >= 0 && emask[e]) ? 1 : 0;
  ei0[e] = keep ? nr : 0;
  ei1[e] = keep ? nc : 0;
  ewf[e] = keep ? ewf[e] : 0.f;
  emask[e] = keep;
}
__global__ void reps_kernel(const float* __restrict__ h, float* rep, int k) {
  int g = blockIdx.x, c = threadIdx.x;
  float mx = -3.4e38f, sm = 0.f;
  for (int j = 0; j < k; j++) {
    float v = h[(size_t)(g * k + j) * 128 + c];
    mx = fmaxf(mx, v);
    sm += v;
  }
  rep[g * 256 + c] = mx;
  rep[g * 256 + 128 + c] = sm / (float)k;
}
__global__ void final_out(const float* __restrict__ r0, const float* __restrict__ r1,
                          float* out) {
  int t = blockIdx.x * blockDim.x + threadIdx.x;
  if (t >= NB * 256) return;
  out[t] = r0[t] + r1[t];
}

// NaN stage check: writes sentinel to out[slot] only if NaN found
__global__ void nan_check(const float* __restrict__ buf, int n, float* out, int slot,
                          float code) {
  int i = blockIdx.x * blockDim.x + threadIdx.x;
  if (i >= n) return;
  float v = buf[i];
  if (v != v) out[slot] = code;
}
// diagnostic: writes only on anomaly
__global__ void diag_kernel(const float* __restrict__ x, float* out, int ws_ok) {
  int lane = threadIdx.x;
  float v = x[lane];
  unsigned long long zm = __ballot(v == 0.f);
  unsigned long long bm = __ballot(fabsf(v) > 1e3f);
  if (lane == 0) {
    if (zm == ~0ull) out[0] = 1000.f;
    if (bm != 0ull) out[1] = 2000.f;
    if (!ws_ok) out[2] = 3000.f;
  }
}

extern "C" __attribute__((visibility("default")))
void kernel_launch(void* const* d_in, const int* in_sizes, int n_in,
                   void* d_out, int out_size, void* d_ws, size_t ws_size,
                   hipStream_t stream) {
  (void)hipGetLastError();

  const float* x = (const float*)d_in[0];
  const float* edge_attr = (const float*)d_in[1];
  const int* edge_index = (const int*)d_in[2];
  const float* edge_weight = (const float*)d_in[3];
  const float* lin0_w = (const float*)d_in[5];
  const float* lin0_b = (const float*)d_in[6];
  const float* lin_w = (const float*)d_in[7];
  const float* lin_b = (const float*)d_in[8];
  const float* q_w = (const float*)d_in[9];
  const float* q_b = (const float*)d_in[10];
  const float* k_w = (const float*)d_in[11];
  const float* k_b = (const float*)d_in[12];
  const float* v_w = (const float*)d_in[13];
  const float* v_b = (const float*)d_in[14];
  const float* e_w = (const float*)d_in[15];
  const float* e_b = (const float*)d_in[16];
  const float* s_w = (const float*)d_in[17];
  const float* s_b = (const float*)d_in[18];
  const float* tr_w = (const float*)d_in[19];
  const float* tr_b = (const float*)d_in[20];
  const float* bn_g = (const float*)d_in[21];
  const float* bn_b = (const float*)d_in[22];
  const float* pool_w = (const float*)d_in[23];
  (void)in_sizes; (void)n_in;

  float* out = (float*)d_out;

  size_t off = 0;
  auto alloc = [&](size_t bytes) -> void* {
    void* r = (char*)d_ws + off;
    off += (bytes + 255) & ~(size_t)255;
    return r;
  };
  float* P0 = (float*)alloc((size_t)NNODES * 128 * 4);
  float* P1 = (float*)alloc((size_t)NNODES * 128 * 4);
  float* XL = (float*)alloc((size_t)NNODES * 128 * 4);
  float* U = (float*)alloc((size_t)NNODES * 512 * 4);  // fused_attn OUT aliases U
  float* G = (float*)alloc((size_t)NNODES * 256 * 4);
  float* SCV = (float*)alloc((size_t)NNODES * 8 * 4);
  float* Ct = (float*)alloc(128 * 512 * 4);
  float* Bt = (float*)alloc(128 * 256 * 4);
  float* GB = (float*)alloc(256 * 4);
  float* WCR = (float*)alloc(128 * 8 * 4);
  float* CC = (float*)alloc(4 * 4);
  float* DIS = (float*)alloc((size_t)NNODES * 4);
  int* EI0 = (int*)alloc((size_t)NEDGES * 4);
  int* EI1 = (int*)alloc((size_t)NEDGES * 4);
  float* EWF = (float*)alloc((size_t)NEDGES * 4);
  int* EMASK = (int*)alloc((size_t)NEDGES * 4);
  int* CNT = (int*)alloc((size_t)NNODES * 4);
  int* INDPTR = (int*)alloc((size_t)(NNODES + 1) * 4);
  int* CURSOR = (int*)alloc((size_t)NNODES * 4);
  int* CSRE = (int*)alloc((size_t)NEDGES * 4);
  float* SCORE = (float*)alloc((size_t)NNODES * 4);
  int* NEWID = (int*)alloc((size_t)NNODES * 4);
  int* SELI = (int*)alloc((size_t)16384 * 4);
  float* GATEV = (float*)alloc((size_t)16384 * 4);
  float* REPS0 = (float*)alloc((size_t)NB * 256 * 4);
  float* REPS1 = (float*)alloc((size_t)NB * 256 * 4);
  float* S1 = (float*)alloc(128 * 4);
  float* S2 = (float*)alloc(128 * 4);
  float* MU = (float*)alloc(128 * 4);
  float* RSTD = (float*)alloc(128 * 4);
  float* WN = (float*)alloc(256);
  const int ws_ok = (ws_size >= off) ? 1 : 0;

  edge_init<<<NEDGES / 256, 256, 0, stream>>>(edge_index, edge_weight, EI0, EI1, EWF, EMASK);
  if (hipGetLastError() != hipSuccess) {
    stream = (hipStream_t)0;
    edge_init<<<NEDGES / 256, 256, 0, stream>>>(edge_index, edge_weight, EI0, EI1, EWF, EMASK);
    (void)hipGetLastError();
  }

  if (!ws_ok) {
    fill_f32<<<(out_size + 255) / 256, 256, 0, stream>>>(out, 3000.f, out_size);
    diag_kernel<<<1, 64, 0, stream>>>(x, out, ws_ok);
    return;
  }

  auto conv = [&](int n, const float* Ain, int K0, float* Pout, const float* lw,
                  const float* lb, int l) {
    const float* qwl = q_w + (size_t)l * 128 * 512;
    const float* qbl = q_b + (size_t)l * 512;
    const float* kwl = k_w + (size_t)l * 128 * 512;
    const float* kbl = k_b + (size_t)l * 512;
    const float* vwl = v_w + (size_t)l * 128 * 512;
    const float* vbl = v_b + (size_t)l * 512;
    const float* ewl = e_w + (size_t)l * 64 * 512;
    const float* ebl = e_b + (size_t)l * 512;
    const float* swl = s_w + (size_t)l * 128 * 512;
    const float* sbl = s_b + (size_t)l * 512;
    const float* trwl = tr_w + (size_t)l * 512 * 128;
    const float* trbl = tr_b + (size_t)l * 128;

    prep_ct<<<256, 256, 0, stream>>>(qwl, kwl, Ct);
    prep_bt<<<128, 256, 0, stream>>>(qwl, ewl, qbl, Bt, GB);
    prep_sc<<<1, 1024, 0, stream>>>(qwl, kwl, qbl, kbl, ebl, WCR, CC);

    gemm_bias<<<dim3(n / 64, 2), 256, 0, stream>>>(Ain, lw, lb, XL, n, K0, 128, 0);
    gemm_bias<<<dim3(n / 64, 8), 256, 0, stream>>>(XL, Ct, nullptr, U, n, 128, 512, 0);
    gemm_bias<<<dim3(n / 64, 4), 256, 0, stream>>>(XL, Bt, GB, G, n, 128, 256, 0);
    node_scalars<<<n / 32, 256, 0, stream>>>(XL, WCR, CC, SCV, n);

    fill_f32<<<(n + 255) / 256, 256, 0, stream>>>(DIS, 0.f, n);
    deg_count<<<NEDGES / 256, 256, 0, stream>>>(EI0, EMASK, DIS);
    dis_finish<<<(n + 255) / 256, 256, 0, stream>>>(DIS, n);

    fill_i32<<<(n + 255) / 256, 256, 0, stream>>>(CNT, 0, n);
    cnt_count<<<NEDGES / 256, 256, 0, stream>>>(EI1, EMASK, CNT);
    scan_kernel<<<1, 1024, 0, stream>>>(CNT, INDPTR, CURSOR, n);
    csr_fill<<<NEDGES / 256, 256, 0, stream>>>(EI1, EMASK, CURSOR, CSRE);

    fused_attn<<<n / 4, 256, 0, stream>>>(EI0, EWF, INDPTR, CSRE, edge_attr, XL, U, G,
                                          SCV, DIS, vwl, ewl, swl, vbl, ebl, sbl, U);

    gemm_bias<<<dim3(n / 64, 2), 256, 0, stream>>>(U, trwl, trbl, Pout, n, 512, 128, 1);
    fill_f32<<<1, 128, 0, stream>>>(S1, 0.f, 128);
    fill_f32<<<1, 128, 0, stream>>>(S2, 0.f, 128);
    bn_accum<<<64, 256, 0, stream>>>(Pout, S1, S2, n);
    bn_final<<<1, 128, 0, stream>>>(S1, S2, MU, RSTD, n);
    bn_apply<<<(n * 128) / 256, 256, 0, stream>>>(Pout, MU, RSTD, bn_g + l * 128,
                                                  bn_b + l * 128, n);
  };

  auto pool = [&](int pi, const float* hSrc, float* hDst, int nOld, int M, float* reps) {
    wnorm_kernel<<<1, 128, 0, stream>>>(pool_w + pi * 128, WN);
    score_kernel<<<(nOld + 255) / 256, 256, 0, stream>>>(hSrc, pool_w + pi * 128, WN,
                                                         SCORE, nOld);
    fill_i32<<<(nOld + 255) / 256, 256, 0, stream>>>(NEWID, -1, nOld);
    topk_kernel<<<NB, 512, 0, stream>>>(SCORE, GATEV, SELI, NEWID, M);
    int nNew = nOld / 2;
    gate_kernel<<<(nNew * 128) / 256, 256, 0, stream>>>(hSrc, GATEV, SELI, hDst, nNew);
    relabel_kernel<<<NEDGES / 256, 256, 0, stream>>>(EI0, EI1, EWF, EMASK, NEWID);
    reps_kernel<<<NB, 128, 0, stream>>>(hDst, reps, M / 2);
  };

  conv(NNODES, x, 256, P0, lin0_w, lin0_b, 0);
  conv(NNODES, P0, 128, P1, lin_w, lin_b, 1);
  pool(0, P1, P0, NNODES, 1024, REPS0);
  conv(16384, P0, 128, P1, lin_w + 128 * 128, lin_b + 128, 2);
  conv(16384, P1, 128, P0, lin_w + 2 * 128 * 128, lin_b + 2 * 128, 3);
  pool(1, P0, P1, 16384, 512, REPS1);

  final_out<<<NB * 256 / 256, 256, 0, stream>>>(REPS0, REPS1, out);

  nan_check<<<(NNODES * 128) / 256, 256, 0, stream>>>(P0, NNODES * 128, out, 3, 500.f);
  nan_check<<<(NB * 256) / 256, 256, 0, stream>>>(REPS0, NB * 256, out, 4, 600.f);
  diag_kernel<<<1, 64, 0, stream>>>(x, out, ws_ok);

  if (hipGetLastError() != hipSuccess) {
    hipMemsetAsync(d_out, 0x45, (size_t)out_size * 4, stream);
  }
}

// Round 8
// 3164.169 us; speedup vs baseline: 1.3104x; 1.3104x over previous
//
#include <hip/hip_runtime.h>
#include <math.h>
#include <cstddef>

#define NNODES 32768
#define NEDGES 262144
#define NB 32
#define CH 8192  // epilogue chunk rows

__device__ __forceinline__ void load8f(const float* p, float* o) {
  float4 a = *reinterpret_cast<const float4*>(p);
  float4 b = *reinterpret_cast<const float4*>(p + 4);
  o[0] = a.x; o[1] = a.y; o[2] = a.z; o[3] = a.w;
  o[4] = b.x; o[5] = b.y; o[6] = b.z; o[7] = b.w;
}

__global__ void GraphEncoder_82575041233261_kernel() {}

__global__ void fill_f32(float* p, float v, int n) {
  int i = blockIdx.x * blockDim.x + threadIdx.x;
  if (i < n) p[i] = v;
}
__global__ void fill_i32(int* p, int v, int n) {
  int i = blockIdx.x * blockDim.x + threadIdx.x;
  if (i < n) p[i] = v;
}

__global__ void edge_init(const int* __restrict__ ei, const float* __restrict__ ew,
                          int* ei0, int* ei1, float* ewf, int* emask) {
  int e = blockIdx.x * blockDim.x + threadIdx.x;
  if (e >= NEDGES) return;
  ei0[e] = ei[e];
  ei1[e] = ei[NEDGES + e];
  ewf[e] = ew[e];
  emask[e] = 1;
}

// C[n,M] = A[n,K] @ W[K,M] (+bias) (relu optional). 64x64 tile, 256 thr.
__global__ __launch_bounds__(256) void gemm_bias(
    const float* __restrict__ A, const float* __restrict__ W,
    const float* __restrict__ bias, float* __restrict__ C,
    int n, int K, int M, int relu) {
  __shared__ float As[16][64];
  __shared__ float Ws[16][64];
  const int tid = threadIdx.x;
  const int tx = tid & 15, ty = tid >> 4;
  const int row0 = blockIdx.x * 64, col0 = blockIdx.y * 64;
  float acc[4][4] = {{0.f}, {0.f}, {0.f}, {0.f}};
  for (int kt = 0; kt < K; kt += 16) {
#pragma unroll
    for (int i = 0; i < 4; i++) {
      int idx = tid + i * 256;
      int m = idx >> 4, kk = idx & 15;
      As[kk][m] = A[(size_t)(row0 + m) * K + kt + kk];
    }
#pragma unroll
    for (int i = 0; i < 4; i++) {
      int idx = tid + i * 256;
      int nn = idx & 63, kk = idx >> 6;
      Ws[kk][nn] = W[(size_t)(kt + kk) * M + col0 + nn];
    }
    __syncthreads();
#pragma unroll
    for (int kk = 0; kk < 16; kk++) {
      float a[4], b[4];
#pragma unroll
      for (int i = 0; i < 4; i++) a[i] = As[kk][ty * 4 + i];
#pragma unroll
      for (int j = 0; j < 4; j++) b[j] = Ws[kk][tx * 4 + j];
#pragma unroll
      for (int i = 0; i < 4; i++)
#pragma unroll
        for (int j = 0; j < 4; j++) acc[i][j] += a[i] * b[j];
    }
    __syncthreads();
  }
#pragma unroll
  for (int i = 0; i < 4; i++)
#pragma unroll
    for (int j = 0; j < 4; j++) {
      int cc = col0 + tx * 4 + j;
      float v = acc[i][j] + (bias ? bias[cc] : 0.f);
      if (relu) v = fmaxf(v, 0.f);
      C[(size_t)(row0 + ty * 4 + i) * M + cc] = v;
    }
}

// Ct[cin, h*128+co] = sum_c Wq[cin,h128+c]*Wk[co,h128+c]
__global__ __launch_bounds__(256) void prep_ct(const float* __restrict__ Wq,
                                               const float* __restrict__ Wk,
                                               float* __restrict__ Ct) {
  int idx = blockIdx.x * 256 + threadIdx.x;  // 65536
  int cin = idx >> 9, r = idx & 511, h = r >> 7, co = r & 127;
  float acc = 0.f;
  for (int c = 0; c < 128; c++)
    acc += Wq[cin * 512 + h * 128 + c] * Wk[co * 512 + h * 128 + c];
  Ct[idx] = acc;
}
// Bt[cin, h*64+f] = sum_c Wq[cin,h128+c]*EWm[f,h128+c]; gb[h64+f]=sum_c EWm*bq
__global__ __launch_bounds__(256) void prep_bt(const float* __restrict__ Wq,
                                               const float* __restrict__ EWm,
                                               const float* __restrict__ bq,
                                               float* __restrict__ Bt, float* __restrict__ gb) {
  int idx = blockIdx.x * 256 + threadIdx.x;  // 32768
  int cin = idx >> 8, r = idx & 255, h = r >> 6, f = r & 63;
  float acc = 0.f;
  for (int c = 0; c < 128; c++)
    acc += Wq[cin * 512 + h * 128 + c] * EWm[f * 512 + h * 128 + c];
  Bt[idx] = acc;
  if (cin == 0) {
    float s = 0.f;
    for (int c = 0; c < 128; c++)
      s += EWm[f * 512 + h * 128 + c] * bq[h * 128 + c];
    gb[r] = s;
  }
}
// WCR[cin,j]: j<4 -> colS (Wq*(bk+eb)); j>=4 -> rowS (Wk*bq). CC[h]=bq*(bk+eb)
__global__ __launch_bounds__(1024) void prep_sc(const float* __restrict__ Wq,
                                                const float* __restrict__ Wk,
                                                const float* __restrict__ bq,
                                                const float* __restrict__ bk,
                                                const float* __restrict__ eb,
                                                float* __restrict__ WCR, float* __restrict__ CC) {
  int tid = threadIdx.x;
  int cin = tid >> 3, j = tid & 7, h = j & 3, isR = j >> 2;
  float acc = 0.f;
  if (isR) {
    for (int c = 0; c < 128; c++)
      acc += Wk[cin * 512 + h * 128 + c] * bq[h * 128 + c];
  } else {
    for (int c = 0; c < 128; c++)
      acc += Wq[cin * 512 + h * 128 + c] * (bk[h * 128 + c] + eb[h * 128 + c]);
  }
  WCR[cin * 8 + j] = acc;
  if (tid < 4) {
    float s = 0.f;
    for (int c = 0; c < 128; c++)
      s += bq[tid * 128 + c] * (bk[tid * 128 + c] + eb[tid * 128 + c]);
    CC[tid] = s;
  }
}
// SCV[node, j] = XL[node]·WCR[:,j] (+CC for j<4)
__global__ __launch_bounds__(256) void node_scalars(const float* __restrict__ XL,
                                                    const float* __restrict__ WCR,
                                                    const float* __restrict__ CC,
                                                    float* __restrict__ SCV, int n) {
  int t = blockIdx.x * 256 + threadIdx.x;
  if (t >= n * 8) return;
  int node = t >> 3, j = t & 7;
  const float* xr = XL + (size_t)node * 128;
  float acc = (j < 4) ? CC[j] : 0.f;
  for (int c = 0; c < 128; c++) acc += xr[c] * WCR[c * 8 + j];
  SCV[t] = acc;
}

__global__ void deg_count(const int* __restrict__ ei0, const int* __restrict__ emask,
                          float* deg) {
  int e = blockIdx.x * blockDim.x + threadIdx.x;
  if (e >= NEDGES) return;
  if (emask[e]) atomicAdd(&deg[ei0[e]], 1.0f);
}
__global__ void dis_finish(float* dis, int n) {
  int i = blockIdx.x * blockDim.x + threadIdx.x;
  if (i >= n) return;
  float d = dis[i];
  dis[i] = d > 0.f ? rsqrtf(d) : 0.f;
}
__global__ void cnt_count(const int* __restrict__ ei1, const int* __restrict__ emask,
                          int* cnt) {
  int e = blockIdx.x * blockDim.x + threadIdx.x;
  if (e >= NEDGES) return;
  if (emask[e]) atomicAdd(&cnt[ei1[e]], 1);
}
__global__ __launch_bounds__(1024) void scan_kernel(const int* __restrict__ cnt,
                                                    int* indptr, int* cursor, int n) {
  __shared__ int part[1024];
  int tid = threadIdx.x;
  int per = n / 1024;
  int base = tid * per;
  int s = 0;
  for (int j = 0; j < per; j++) s += cnt[base + j];
  part[tid] = s;
  __syncthreads();
  for (int d = 1; d < 1024; d <<= 1) {
    int t = (tid >= d) ? part[tid - d] : 0;
    __syncthreads();
    part[tid] += t;
    __syncthreads();
  }
  int run = part[tid] - s;  // exclusive
  for (int j = 0; j < per; j++) {
    indptr[base + j] = run;
    cursor[base + j] = run;
    run += cnt[base + j];
  }
  if (tid == 1023) indptr[n] = run;
}
__global__ void csr_fill(const int* __restrict__ ei1, const int* __restrict__ emask,
                         int* cursor, int* csre) {
  int e = blockIdx.x * blockDim.x + threadIdx.x;
  if (e >= NEDGES) return;
  if (!emask[e]) return;
  int p = atomicAdd(&cursor[ei1[e]], 1);
  csre[p] = e;
}

// ---- light attention pass: one wave per destination node, online softmax.
// Reads own U/G row into registers, then overwrites them with Z/WS (safe:
// no other wave touches this row).
__global__ __launch_bounds__(256) void fused_attn_light(
    const int* __restrict__ EI0v, const float* __restrict__ EWFv,
    const int* __restrict__ indptr, const int* __restrict__ csre,
    const float* __restrict__ EA, const float* __restrict__ XLv,
    float* U, float* G, const float* __restrict__ SCVv,
    const float* __restrict__ DISv, float* __restrict__ XW,
    float* __restrict__ DEN) {
  const int w = threadIdx.x >> 6, lane = threadIdx.x & 63;
  const int h = lane >> 4, t16 = lane & 15;
  const int col = blockIdx.x * 4 + w;
  float u8[8];
  load8f(U + (size_t)col * 512 + lane * 8, u8);
  float4 g4 = *reinterpret_cast<const float4*>(G + (size_t)col * 256 + lane * 4);
  const float colS = SCVv[col * 8 + h];
  const float dcol = DISv[col];
  const int beg = indptr[col], end = indptr[col + 1];
  const float rs = 0.08838834764831845f;  // 1/sqrt(128)
  float m = -3.0e38f, den = 0.f;
  float z8[8] = {0.f, 0.f, 0.f, 0.f, 0.f, 0.f, 0.f, 0.f};
  float w4[4] = {0.f, 0.f, 0.f, 0.f};
  float xw0 = 0.f, xw1 = 0.f;
  for (int i = beg; i < end; i++) {
    const int e = csre[i];
    const int r = EI0v[e];
    float xr[8];
    load8f(XLv + (size_t)r * 128 + t16 * 8, xr);
    float4 ea4 = *reinterpret_cast<const float4*>(EA + (size_t)e * 64 + t16 * 4);
    float pa = 0.f;
#pragma unroll
    for (int j = 0; j < 8; j++) pa += u8[j] * xr[j];
    pa += g4.x * ea4.x + g4.y * ea4.y + g4.z * ea4.z + g4.w * ea4.w;
    pa += __shfl_xor(pa, 1);
    pa += __shfl_xor(pa, 2);
    pa += __shfl_xor(pa, 4);
    pa += __shfl_xor(pa, 8);
    const float alpha = (pa + colS + SCVv[r * 8 + 4 + h]) * rs;
    const float mn = fmaxf(m, alpha);
    const float sc = expf(m - mn);   // 0 on first iter (m=-3e38)
    const float a = expf(alpha - mn);
    den = den * sc + a;
#pragma unroll
    for (int j = 0; j < 8; j++) z8[j] = z8[j] * sc + a * xr[j];
    w4[0] = w4[0] * sc + a * ea4.x;
    w4[1] = w4[1] * sc + a * ea4.y;
    w4[2] = w4[2] * sc + a * ea4.z;
    w4[3] = w4[3] * sc + a * ea4.w;
    m = mn;
    const float norm = DISv[r] * EWFv[e] * dcol;
    xw0 += norm * XLv[(size_t)r * 128 + lane * 2];
    xw1 += norm * XLv[(size_t)r * 128 + lane * 2 + 1];
  }
  float4 o1, o2;
  o1.x = z8[0]; o1.y = z8[1]; o1.z = z8[2]; o1.w = z8[3];
  o2.x = z8[4]; o2.y = z8[5]; o2.z = z8[6]; o2.w = z8[7];
  *reinterpret_cast<float4*>(U + (size_t)col * 512 + lane * 8) = o1;
  *reinterpret_cast<float4*>(U + (size_t)col * 512 + lane * 8 + 4) = o2;
  float4 ow;
  ow.x = w4[0]; ow.y = w4[1]; ow.z = w4[2]; ow.w = w4[3];
  *reinterpret_cast<float4*>(G + (size_t)col * 256 + lane * 4) = ow;
  float2 oxw; oxw.x = xw0; oxw.y = xw1;
  *reinterpret_cast<float2*>(XW + (size_t)col * 128 + lane * 2) = oxw;
  if (t16 == 0) DEN[col * 4 + h] = den;
}

// ---- epilogue GEMM: ATTN[row,col] for col in head h's 128-range:
//  pre = Z[row,h*128+:]@Wv[:,col] + WS[row,h*64+:]@EWm[:,col] + den*(vb+eb)
//  attn = pre/(den+1e-16) + sb + XL[row,:]@Sw[:,col] + XW[row,col&127]
__global__ __launch_bounds__(256) void attn_gemm(
    const float* __restrict__ Z, const float* __restrict__ WS,
    const float* __restrict__ XLv, const float* __restrict__ XW,
    const float* __restrict__ DEN, const float* __restrict__ Wv,
    const float* __restrict__ EWm, const float* __restrict__ Sw,
    const float* __restrict__ vb, const float* __restrict__ eb,
    const float* __restrict__ sb, float* __restrict__ ATTN, int rowBase) {
  __shared__ float As[16][64];
  __shared__ float Bs[16][64];
  const int tid = threadIdx.x;
  const int tx = tid & 15, ty = tid >> 4;
  const int row0 = rowBase + blockIdx.x * 64;
  const int col0 = blockIdx.y * 64;
  const int h = blockIdx.y >> 1;
  float acc[4][4] = {{0.f}, {0.f}, {0.f}, {0.f}};
  // phase A: K=128 over Z (head-offset)
  for (int kt = 0; kt < 128; kt += 16) {
#pragma unroll
    for (int i = 0; i < 4; i++) {
      int idx = tid + i * 256;
      int mm = idx >> 4, kk = idx & 15;
      As[kk][mm] = Z[(size_t)(row0 + mm) * 512 + h * 128 + kt + kk];
    }
#pragma unroll
    for (int i = 0; i < 4; i++) {
      int idx = tid + i * 256;
      int nn = idx & 63, kk = idx >> 6;
      Bs[kk][nn] = Wv[(size_t)(kt + kk) * 512 + col0 + nn];
    }
    __syncthreads();
#pragma unroll
    for (int kk = 0; kk < 16; kk++) {
      float a[4], b[4];
#pragma unroll
      for (int i = 0; i < 4; i++) a[i] = As[kk][ty * 4 + i];
#pragma unroll
      for (int j = 0; j < 4; j++) b[j] = Bs[kk][tx * 4 + j];
#pragma unroll
      for (int i = 0; i < 4; i++)
#pragma unroll
        for (int j = 0; j < 4; j++) acc[i][j] += a[i] * b[j];
    }
    __syncthreads();
  }
  // phase B: K=64 over WS (head-offset)
  for (int kt = 0; kt < 64; kt += 16) {
#pragma unroll
    for (int i = 0; i < 4; i++) {
      int idx = tid + i * 256;
      int mm = idx >> 4, kk = idx & 15;
      As[kk][mm] = WS[(size_t)(row0 + mm) * 256 + h * 64 + kt + kk];
    }
#pragma unroll
    for (int i = 0; i < 4; i++) {
      int idx = tid + i * 256;
      int nn = idx & 63, kk = idx >> 6;
      Bs[kk][nn] = EWm[(size_t)(kt + kk) * 512 + col0 + nn];
    }
    __syncthreads();
#pragma unroll
    for (int kk = 0; kk < 16; kk++) {
      float a[4], b[4];
#pragma unroll
      for (int i = 0; i < 4; i++) a[i] = As[kk][ty * 4 + i];
#pragma unroll
      for (int j = 0; j < 4; j++) b[j] = Bs[kk][tx * 4 + j];
#pragma unroll
      for (int i = 0; i < 4; i++)
#pragma unroll
        for (int j = 0; j < 4; j++) acc[i][j] += a[i] * b[j];
    }
    __syncthreads();
  }
  // mid: den scaling + biases
#pragma unroll
  for (int i = 0; i < 4; i++) {
    const float d = DEN[(size_t)(row0 + ty * 4 + i) * 4 + h];
    const float inv = 1.f / (d + 1e-16f);
#pragma unroll
    for (int j = 0; j < 4; j++) {
      int cc = col0 + tx * 4 + j;
      acc[i][j] = (acc[i][j] + d * (vb[cc] + eb[cc])) * inv + sb[cc];
    }
  }
  // phase C: K=128 over XL (skip branch)
  for (int kt = 0; kt < 128; kt += 16) {
#pragma unroll
    for (int i = 0; i < 4; i++) {
      int idx = tid + i * 256;
      int mm = idx >> 4, kk = idx & 15;
      As[kk][mm] = XLv[(size_t)(row0 + mm) * 128 + kt + kk];
    }
#pragma unroll
    for (int i = 0; i < 4; i++) {
      int idx = tid + i * 256;
      int nn = idx & 63, kk = idx >> 6;
      Bs[kk][nn] = Sw[(size_t)(kt + kk) * 512 + col0 + nn];
    }
    __syncthreads();
#pragma unroll
    for (int kk = 0; kk < 16; kk++) {
      float a[4], b[4];
#pragma unroll
      for (int i = 0; i < 4; i++) a[i] = As[kk][ty * 4 + i];
#pragma unroll
      for (int j = 0; j < 4; j++) b[j] = Bs[kk][tx * 4 + j];
#pragma unroll
      for (int i = 0; i < 4; i++)
#pragma unroll
        for (int j = 0; j < 4; j++) acc[i][j] += a[i] * b[j];
    }
    __syncthreads();
  }
#pragma unroll
  for (int i = 0; i < 4; i++)
#pragma unroll
    for (int j = 0; j < 4; j++) {
      int cc = col0 + tx * 4 + j;
      float v = acc[i][j] + XW[(size_t)(row0 + ty * 4 + i) * 128 + (cc & 127)];
      ATTN[(size_t)(blockIdx.x * 64 + ty * 4 + i) * 512 + cc] = v;
    }
}

// ---- batchnorm (in-place) ----
__global__ __launch_bounds__(256) void bn_accum(const float* __restrict__ x,
                                                float* s1, float* s2, int n) {
  int c = threadIdx.x & 127;
  int half = threadIdx.x >> 7;
  float a = 0.f, b = 0.f;
  for (int i = blockIdx.x * 2 + half; i < n; i += gridDim.x * 2) {
    float v = x[(size_t)i * 128 + c];
    a += v;
    b += v * v;
  }
  atomicAdd(&s1[c], a);
  atomicAdd(&s2[c], b);
}
__global__ void bn_final(const float* s1, const float* s2, float* mu, float* rstd, int n) {
  int c = threadIdx.x;
  if (c >= 128) return;
  float m = s1[c] / (float)n;
  mu[c] = m;
  float var = s2[c] / (float)n - m * m;
  rstd[c] = rsqrtf(var + 1e-5f);
}
__global__ void bn_apply(float* x, const float* __restrict__ mu,
                         const float* __restrict__ rstd, const float* __restrict__ g,
                         const float* __restrict__ b, int n) {
  int t = blockIdx.x * blockDim.x + threadIdx.x;
  if (t >= n * 128) return;
  int c = t & 127;
  x[t] = g[c] * (x[t] - mu[c]) * rstd[c] + b[c];
}

// ---- pooling ----
__global__ void wnorm_kernel(const float* __restrict__ w, float* wn) {
  __shared__ float s[128];
  int t = threadIdx.x;
  float v = w[t];
  s[t] = v * v;
  __syncthreads();
  for (int st = 64; st > 0; st >>= 1) {
    if (t < st) s[t] += s[t + st];
    __syncthreads();
  }
  if (t == 0) wn[0] = sqrtf(s[0]) + 1e-16f;
}
__global__ void score_kernel(const float* __restrict__ h, const float* __restrict__ w,
                             const float* __restrict__ wn, float* s, int n) {
  int i = blockIdx.x * blockDim.x + threadIdx.x;
  if (i >= n) return;
  float d = 0.f;
  for (int c = 0; c < 128; c++) d += h[(size_t)i * 128 + c] * w[c];
  s[i] = tanhf(d / wn[0]);
}
__global__ __launch_bounds__(512) void topk_kernel(const float* __restrict__ s,
                                                   float* gateVal, int* selIdx,
                                                   int* newid, int M) {
  __shared__ float sv[1024];
  __shared__ int si[1024];
  const int g = blockIdx.x;
  const int k = M >> 1;
  for (int t = threadIdx.x; t < 1024; t += 512) {
    if (t < M) {
      sv[t] = s[(size_t)g * M + t];
      si[t] = t;
    } else {
      sv[t] = -3.4e38f;
      si[t] = 0x7fffffff;
    }
  }
  __syncthreads();
  for (int kk = 2; kk <= 1024; kk <<= 1) {
    for (int j = kk >> 1; j > 0; j >>= 1) {
      for (int t = threadIdx.x; t < 1024; t += 512) {
        int p = t ^ j;
        if (p > t) {
          float va = sv[t], vb2 = sv[p];
          int ia = si[t], ib = si[p];
          bool beforeBA = (vb2 > va) || (vb2 == va && ib < ia);
          bool beforeAB = (va > vb2) || (va == vb2 && ia < ib);
          bool dir = ((t & kk) == 0);
          bool sw = dir ? beforeBA : beforeAB;
          if (sw) {
            sv[t] = vb2;
            sv[p] = va;
            si[t] = ib;
            si[p] = ia;
          }
        }
      }
      __syncthreads();
    }
  }
  for (int j = threadIdx.x; j < k; j += 512) {
    int oldg = g * M + si[j];
    int newg = g * k + j;
    gateVal[newg] = sv[j];
    selIdx[newg] = oldg;
    newid[oldg] = newg;
  }
}
__global__ void gate_kernel(const float* __restrict__ hOld, const float* __restrict__ gv,
                            const int* __restrict__ sel, float* __restrict__ hNew,
                            int nNew) {
  int t = blockIdx.x * blockDim.x + threadIdx.x;
  if (t >= nNew * 128) return;
  int i = t >> 7, c = t & 127;
  hNew[t] = hOld[(size_t)sel[i] * 128 + c] * gv[i];
}
__global__ void relabel_kernel(int* ei0, int* ei1, float* ewf, int* emask,
                               const int* __restrict__ newid) {
  int e = blockIdx.x * blockDim.x + threadIdx.x;
  if (e >= NEDGES) return;
  int nr = newid[ei0[e]];
  int nc = newid[ei1[e]];
  int keep = (nr >= 0 && nc >= 0 && emask[e]) ? 1 : 0;
  ei0[e] = keep ? nr : 0;
  ei1[e] = keep ? nc : 0;
  ewf[e] = keep ? ewf[e] : 0.f;
  emask[e] = keep;
}
__global__ void reps_kernel(const float* __restrict__ h, float* rep, int k) {
  int g = blockIdx.x, c = threadIdx.x;
  float mx = -3.4e38f, sm = 0.f;
  for (int j = 0; j < k; j++) {
    float v = h[(size_t)(g * k + j) * 128 + c];
    mx = fmaxf(mx, v);
    sm += v;
  }
  rep[g * 256 + c] = mx;
  rep[g * 256 + 128 + c] = sm / (float)k;
}
__global__ void final_out(const float* __restrict__ r0, const float* __restrict__ r1,
                          float* out) {
  int t = blockIdx.x * blockDim.x + threadIdx.x;
  if (t >= NB * 256) return;
  out[t] = r0[t] + r1[t];
}

extern "C" __attribute__((visibility("default")))
void kernel_launch(void* const* d_in, const int* in_sizes, int n_in,
                   void* d_out, int out_size, void* d_ws, size_t ws_size,
                   hipStream_t stream) {
  (void)hipGetLastError();

  const float* x = (const float*)d_in[0];
  const float* edge_attr = (const float*)d_in[1];
  const int* edge_index = (const int*)d_in[2];
  const float* edge_weight = (const float*)d_in[3];
  const float* lin0_w = (const float*)d_in[5];
  const float* lin0_b = (const float*)d_in[6];
  const float* lin_w = (const float*)d_in[7];
  const float* lin_b = (const float*)d_in[8];
  const float* q_w = (const float*)d_in[9];
  const float* q_b = (const float*)d_in[10];
  const float* k_w = (const float*)d_in[11];
  const float* k_b = (const float*)d_in[12];
  const float* v_w = (const float*)d_in[13];
  const float* v_b = (const float*)d_in[14];
  const float* e_w = (const float*)d_in[15];
  const float* e_b = (const float*)d_in[16];
  const float* s_w = (const float*)d_in[17];
  const float* s_b = (const float*)d_in[18];
  const float* tr_w = (const float*)d_in[19];
  const float* tr_b = (const float*)d_in[20];
  const float* bn_g = (const float*)d_in[21];
  const float* bn_b = (const float*)d_in[22];
  const float* pool_w = (const float*)d_in[23];
  (void)in_sizes; (void)n_in;

  float* out = (float*)d_out;

  size_t off = 0;
  auto alloc = [&](size_t bytes) -> void* {
    void* r = (char*)d_ws + off;
    off += (bytes + 255) & ~(size_t)255;
    return r;
  };
  float* P0 = (float*)alloc((size_t)NNODES * 128 * 4);
  float* P1 = (float*)alloc((size_t)NNODES * 128 * 4);
  float* XL = (float*)alloc((size_t)NNODES * 128 * 4);
  float* U = (float*)alloc((size_t)NNODES * 512 * 4);  // becomes Z after light pass
  float* G = (float*)alloc((size_t)NNODES * 256 * 4);  // becomes WS after light pass
  float* XW = (float*)alloc((size_t)NNODES * 128 * 4);
  float* DEN = (float*)alloc((size_t)NNODES * 4 * 4);
  float* ATTN = (float*)alloc((size_t)CH * 512 * 4);
  float* SCV = (float*)alloc((size_t)NNODES * 8 * 4);
  float* Ct = (float*)alloc(128 * 512 * 4);
  float* Bt = (float*)alloc(128 * 256 * 4);
  float* GB = (float*)alloc(256 * 4);
  float* WCR = (float*)alloc(128 * 8 * 4);
  float* CC = (float*)alloc(4 * 4);
  float* DIS = (float*)alloc((size_t)NNODES * 4);
  int* EI0 = (int*)alloc((size_t)NEDGES * 4);
  int* EI1 = (int*)alloc((size_t)NEDGES * 4);
  float* EWF = (float*)alloc((size_t)NEDGES * 4);
  int* EMASK = (int*)alloc((size_t)NEDGES * 4);
  int* CNT = (int*)alloc((size_t)NNODES * 4);
  int* INDPTR = (int*)alloc((size_t)(NNODES + 1) * 4);
  int* CURSOR = (int*)alloc((size_t)NNODES * 4);
  int* CSRE = (int*)alloc((size_t)NEDGES * 4);
  float* SCORE = (float*)alloc((size_t)NNODES * 4);
  int* NEWID = (int*)alloc((size_t)NNODES * 4);
  int* SELI = (int*)alloc((size_t)16384 * 4);
  float* GATEV = (float*)alloc((size_t)16384 * 4);
  float* REPS0 = (float*)alloc((size_t)NB * 256 * 4);
  float* REPS1 = (float*)alloc((size_t)NB * 256 * 4);
  float* S1 = (float*)alloc(128 * 4);
  float* S2 = (float*)alloc(128 * 4);
  float* MU = (float*)alloc(128 * 4);
  float* RSTD = (float*)alloc(128 * 4);
  float* WN = (float*)alloc(256);
  const int ws_ok = (ws_size >= off) ? 1 : 0;

  edge_init<<<NEDGES / 256, 256, 0, stream>>>(edge_index, edge_weight, EI0, EI1, EWF, EMASK);
  if (hipGetLastError() != hipSuccess) {
    stream = (hipStream_t)0;
    edge_init<<<NEDGES / 256, 256, 0, stream>>>(edge_index, edge_weight, EI0, EI1, EWF, EMASK);
    (void)hipGetLastError();
  }

  if (!ws_ok) {
    fill_f32<<<(out_size + 255) / 256, 256, 0, stream>>>(out, 3000.f, out_size);
    return;
  }

  auto conv = [&](int n, const float* Ain, int K0, float* Pout, const float* lw,
                  const float* lb, int l) {
    const float* qwl = q_w + (size_t)l * 128 * 512;
    const float* qbl = q_b + (size_t)l * 512;
    const float* kwl = k_w + (size_t)l * 128 * 512;
    const float* kbl = k_b + (size_t)l * 512;
    const float* vwl = v_w + (size_t)l * 128 * 512;
    const float* vbl = v_b + (size_t)l * 512;
    const float* ewl = e_w + (size_t)l * 64 * 512;
    const float* ebl = e_b + (size_t)l * 512;
    const float* swl = s_w + (size_t)l * 128 * 512;
    const float* sbl = s_b + (size_t)l * 512;
    const float* trwl = tr_w + (size_t)l * 512 * 128;
    const float* trbl = tr_b + (size_t)l * 128;

    prep_ct<<<256, 256, 0, stream>>>(qwl, kwl, Ct);
    prep_bt<<<128, 256, 0, stream>>>(qwl, ewl, qbl, Bt, GB);
    prep_sc<<<1, 1024, 0, stream>>>(qwl, kwl, qbl, kbl, ebl, WCR, CC);

    gemm_bias<<<dim3(n / 64, 2), 256, 0, stream>>>(Ain, lw, lb, XL, n, K0, 128, 0);
    gemm_bias<<<dim3(n / 64, 8), 256, 0, stream>>>(XL, Ct, nullptr, U, n, 128, 512, 0);
    gemm_bias<<<dim3(n / 64, 4), 256, 0, stream>>>(XL, Bt, GB, G, n, 128, 256, 0);
    node_scalars<<<n / 32, 256, 0, stream>>>(XL, WCR, CC, SCV, n);

    fill_f32<<<(n + 255) / 256, 256, 0, stream>>>(DIS, 0.f, n);
    deg_count<<<NEDGES / 256, 256, 0, stream>>>(EI0, EMASK, DIS);
    dis_finish<<<(n + 255) / 256, 256, 0, stream>>>(DIS, n);

    fill_i32<<<(n + 255) / 256, 256, 0, stream>>>(CNT, 0, n);
    cnt_count<<<NEDGES / 256, 256, 0, stream>>>(EI1, EMASK, CNT);
    scan_kernel<<<1, 1024, 0, stream>>>(CNT, INDPTR, CURSOR, n);
    csr_fill<<<NEDGES / 256, 256, 0, stream>>>(EI1, EMASK, CURSOR, CSRE);

    fused_attn_light<<<n / 4, 256, 0, stream>>>(EI0, EWF, INDPTR, CSRE, edge_attr, XL,
                                                U, G, SCV, DIS, XW, DEN);

    for (int cb = 0; cb < n; cb += CH) {
      attn_gemm<<<dim3(CH / 64, 8), 256, 0, stream>>>(U, G, XL, XW, DEN, vwl, ewl, swl,
                                                      vbl, ebl, sbl, ATTN, cb);
      gemm_bias<<<dim3(CH / 64, 2), 256, 0, stream>>>(ATTN, trwl, trbl,
                                                      Pout + (size_t)cb * 128, CH, 512,
                                                      128, 1);
    }
    fill_f32<<<1, 128, 0, stream>>>(S1, 0.f, 128);
    fill_f32<<<1, 128, 0, stream>>>(S2, 0.f, 128);
    bn_accum<<<64, 256, 0, stream>>>(Pout, S1, S2, n);
    bn_final<<<1, 128, 0, stream>>>(S1, S2, MU, RSTD, n);
    bn_apply<<<(n * 128) / 256, 256, 0, stream>>>(Pout, MU, RSTD, bn_g + l * 128,
                                                  bn_b + l * 128, n);
  };

  auto pool = [&](int pi, const float* hSrc, float* hDst, int nOld, int M, float* reps) {
    wnorm_kernel<<<1, 128, 0, stream>>>(pool_w + pi * 128, WN);
    score_kernel<<<(nOld + 255) / 256, 256, 0, stream>>>(hSrc, pool_w + pi * 128, WN,
                                                         SCORE, nOld);
    fill_i32<<<(nOld + 255) / 256, 256, 0, stream>>>(NEWID, -1, nOld);
    topk_kernel<<<NB, 512, 0, stream>>>(SCORE, GATEV, SELI, NEWID, M);
    int nNew = nOld / 2;
    gate_kernel<<<(nNew * 128) / 256, 256, 0, stream>>>(hSrc, GATEV, SELI, hDst, nNew);
    relabel_kernel<<<NEDGES / 256, 256, 0, stream>>>(EI0, EI1, EWF, EMASK, NEWID);
    reps_kernel<<<NB, 128, 0, stream>>>(hDst, reps, M / 2);
  };

  conv(NNODES, x, 256, P0, lin0_w, lin0_b, 0);
  conv(NNODES, P0, 128, P1, lin_w, lin_b, 1);
  pool(0, P1, P0, NNODES, 1024, REPS0);
  conv(16384, P0, 128, P1, lin_w + 128 * 128, lin_b + 128, 2);
  conv(16384, P1, 128, P0, lin_w + 2 * 128 * 128, lin_b + 2 * 128, 3);
  pool(1, P0, P1, 16384, 512, REPS1);

  final_out<<<NB * 256 / 256, 256, 0, stream>>>(REPS0, REPS1, out);

  if (hipGetLastError() != hipSuccess) {
    hipMemsetAsync(d_out, 0x45, (size_t)out_size * 4, stream);
  }
}